// Round 9
// baseline (367.945 us; speedup 1.0000x reference)
//
#include <hip/hip_runtime.h>

// ---------------- problem constants ----------------
#define NTOK 8192      // B*T
#define CDIM 1024      // C
#define FDIM 2048      // F
#define NEXP 8         // E
#define CAP  16384     // per-expert list stride
#define NPAIR 16384    // N*K
#define MTCAP 32       // 32*128 = 4096 rows/expert capacity

typedef __bf16 bf16x8 __attribute__((ext_vector_type(8)));
typedef float  f32x4  __attribute__((ext_vector_type(4)));

__device__ __forceinline__ unsigned short f2bf(float f) {
    unsigned int u = __builtin_bit_cast(unsigned int, f);
    unsigned int r = (u + 0x7FFFu + ((u >> 16) & 1u)) >> 16;
    return (unsigned short)r;
}

__device__ __forceinline__ unsigned int pack2(float lo, float hi) {
    return ((unsigned int)f2bf(hi) << 16) | (unsigned int)f2bf(lo);
}

__device__ __forceinline__ float bflo(unsigned int u) {
    return __builtin_bit_cast(float, u << 16);
}
__device__ __forceinline__ float bfhi(unsigned int u) {
    return __builtin_bit_cast(float, u & 0xFFFF0000u);
}

__device__ __forceinline__ void gload_lds16(const void* g, void* l) {
    __builtin_amdgcn_global_load_lds(
        (const __attribute__((address_space(1))) unsigned int*)g,
        (__attribute__((address_space(3))) unsigned int*)l, 16, 0, 0);
}

#define BARRIER() asm volatile("s_barrier" ::: "memory")
#define WAIT_LGKM0() do { asm volatile("s_waitcnt lgkmcnt(0)" ::: "memory"); __builtin_amdgcn_sched_barrier(0); } while (0)
#define WAITVM(n) asm volatile("s_waitcnt vmcnt(" #n ")" ::: "memory")

// ---------------- fp32 -> bf16 bulk convert ----------------
__global__ void cvt_kernel(const float* __restrict__ s, unsigned short* __restrict__ d, long ngrp) {
    long i = (long)blockIdx.x * blockDim.x + threadIdx.x;
    long stride = (long)gridDim.x * blockDim.x;
    const float4* s4 = (const float4*)s;
    uint4* d4 = (uint4*)d;
    for (long g = i; g < ngrp; g += stride) {
        float4 a = s4[2 * g], b = s4[2 * g + 1];
        uint4 o;
        o.x = pack2(a.x, a.y); o.y = pack2(a.z, a.w);
        o.z = pack2(b.x, b.y); o.w = pack2(b.z, b.w);
        d4[g] = o;
    }
}

// ---------------- logits: top-2 + softmax weights, NO atomics ----------------
__global__ __launch_bounds__(256) void logits_kernel(
    const float* __restrict__ x, const float* __restrict__ Wr,
    float* __restrict__ wgt, int* __restrict__ eids)
{
    int w = threadIdx.x >> 6, l = threadIdx.x & 63;
    int t = blockIdx.x * 4 + w;
    const float* xr = x + (size_t)t * CDIM;
    float acc[NEXP];
    #pragma unroll
    for (int e = 0; e < NEXP; e++) acc[e] = 0.f;
    for (int c = l; c < CDIM; c += 64) {
        float xv = xr[c];
        #pragma unroll
        for (int e = 0; e < NEXP; e++) acc[e] += xv * Wr[e * CDIM + c];
    }
    #pragma unroll
    for (int e = 0; e < NEXP; e++)
        for (int off = 32; off > 0; off >>= 1) acc[e] += __shfl_down(acc[e], off);
    if (l == 0) {
        int i0 = 0; float l0 = acc[0];
        #pragma unroll
        for (int e = 1; e < NEXP; e++) if (acc[e] > l0) { l0 = acc[e]; i0 = e; }
        int i1 = -1; float l1 = -3.4e38f;
        #pragma unroll
        for (int e = 0; e < NEXP; e++) if (e != i0 && acc[e] > l1) { l1 = acc[e]; i1 = e; }
        float tv = __expf(l1 - l0);
        float den = 1.f + tv;
        wgt[2 * t] = 1.f / den;
        wgt[2 * t + 1] = tv / den;
        eids[t] = i0 | (i1 << 8);
    }
}

// ---------------- bucket: per-block LDS counters -> 8 global atomics/block ----------------
__global__ __launch_bounds__(256) void bucket_kernel(
    const int* __restrict__ eids, int* __restrict__ list, int* __restrict__ cnt)
{
    __shared__ int lcnt[NEXP];
    __shared__ int lbase[NEXP];
    int t = threadIdx.x;
    if (t < NEXP) lcnt[t] = 0;
    __syncthreads();
    int tok = blockIdx.x * 256 + t;
    int id = eids[tok];
    int e0 = id & 0xff, e1 = (id >> 8) & 0xff;
    int s0 = atomicAdd(&lcnt[e0], 1);
    int s1 = atomicAdd(&lcnt[e1], 1);
    __syncthreads();
    if (t < NEXP) lbase[t] = atomicAdd(&cnt[t], lcnt[t]);
    __syncthreads();
    list[e0 * CAP + lbase[e0] + s0] = 2 * tok;
    list[e1 * CAP + lbase[e1] + s1] = 2 * tok + 1;
}

// ---------------- offs: serial 8-entry prefix sum ----------------
__global__ void offs_kernel(const int* __restrict__ cnt, int* __restrict__ offs) {
    if (threadIdx.x == 0) {
        int a = 0;
        for (int e = 0; e < NEXP; e++) { offs[e] = a; a += cnt[e]; }
    }
}

// ---------------- pack: xg[offs[e]+s] = bf16(x[tok]); wgs[offs[e]+s] = wgt[p] ----------------
__global__ __launch_bounds__(256) void pack_kernel(
    const float* __restrict__ x, const int* __restrict__ list,
    const int* __restrict__ cnt, const int* __restrict__ offs,
    const float* __restrict__ wgt,
    unsigned short* __restrict__ xg, float* __restrict__ wgs)
{
    int e = blockIdx.y;
    int cnt_e = cnt[e];
    int s0 = blockIdx.x * 16;
    if (s0 >= cnt_e) return;
    int t = threadIdx.x;
    int sr = s0 + (t >> 4);
    if (sr >= cnt_e) return;
    int p = list[e * CAP + sr];
    int tok = p >> 1;
    if ((t & 15) == 0) wgs[offs[e] + sr] = wgt[p];
    const float4* src = (const float4*)(x + (size_t)tok * CDIM);
    uint2* dst = (uint2*)(xg + (size_t)(offs[e] + sr) * CDIM);
    int c = t & 15;
    #pragma unroll
    for (int i = 0; i < 16; i++) {
        float4 v = src[c + i * 16];
        uint2 o; o.x = pack2(v.x, v.y); o.y = pack2(v.z, v.w);
        dst[c + i * 16] = o;
    }
}

// ============== GEMM1: dense grouped, 128x64(V+G), BK=64, depth-2 dbuf, counted vmcnt ==============
// 4 waves 2x2; wave = 64 rows x 32 F-cols of V and of G. 64 KB LDS (2 x 32KB buffers).
// Tile t's 8 loads issued at iter t-2; waited with vmcnt(8) (next tile stays in flight).
__global__ __launch_bounds__(256, 2) void gemm1_kernel(
    const unsigned short* __restrict__ xg,    // [NPAIR][CDIM] bf16, slot order
    const unsigned short* __restrict__ W1b,   // [E][2F][CDIM] bf16
    const float* __restrict__ wgs,            // [NPAIR] slot-order router weight
    unsigned short* __restrict__ act,         // [NPAIR][FDIM] bf16, slot order (weighted)
    const int* __restrict__ cnt, const int* __restrict__ offs)
{
    int e = blockIdx.z, nt = blockIdx.x, mt = blockIdx.y;
    int cnt_e = cnt[e];
    if (mt * 128 >= cnt_e) return;
    int off_e = offs[e];

    // per buffer (32KB): A k0 [0,8K) | A k1 [8K,16K) | Bv k0/k1 [16K,24K) | Bg k0/k1 [24K,32K)
    __shared__ __align__(16) char lds[65536];

    int t = threadIdx.x, l = t & 63, w = t >> 6;
    int wave_m = w >> 1, wave_n = w & 1;

    int c2s = ((t & 3) * 16) ^ (((t >> 5) & 1) << 5);
    int dst = t * 16;

    const char *sA0, *sA1, *sBv, *sBg;
    {
        int r0 = min(mt * 128 + (t >> 2), cnt_e - 1);
        int r1 = min(mt * 128 + 64 + (t >> 2), cnt_e - 1);
        sA0 = (const char*)xg + (size_t)(off_e + r0) * 2048 + c2s;
        sA1 = (const char*)xg + (size_t)(off_e + r1) * 2048 + c2s;
        int f = nt * 64 + (t >> 2);
        sBv = (const char*)W1b + ((size_t)e * 2 * FDIM + f) * 2048 + c2s;
        sBg = sBv + (size_t)FDIM * 2048;
    }

    int lane_off = (l & 15) * 64 + (((l >> 4) * 16) ^ (((l >> 3) & 1) << 5));
    f32x4 accV[4][2] = {}, accG[4][2] = {};

#define G1_STAGE(BUF, KB) do { \
        gload_lds16(sA0 + (KB),      (BUF) + dst); \
        gload_lds16(sA1 + (KB),      (BUF) + 4096 + dst); \
        gload_lds16(sA0 + (KB) + 64, (BUF) + 8192 + dst); \
        gload_lds16(sA1 + (KB) + 64, (BUF) + 12288 + dst); \
        gload_lds16(sBv + (KB),      (BUF) + 16384 + dst); \
        gload_lds16(sBv + (KB) + 64, (BUF) + 20480 + dst); \
        gload_lds16(sBg + (KB),      (BUF) + 24576 + dst); \
        gload_lds16(sBg + (KB) + 64, (BUF) + 28672 + dst); \
    } while (0)

    // prologue: tiles 0 and 1 (16 loads outstanding)
    G1_STAGE((char*)lds, 0);
    G1_STAGE((char*)lds + 32768, 128);

    for (int kt = 0; kt < 16; kt++) {
        if (kt == 15) { WAITVM(0); } else { WAITVM(8); }
        BARRIER();

        char* Cur = (char*)lds + (kt & 1) * 32768;
        bf16x8 af[2][4], bv[2][2], bg[2][2];
        #pragma unroll
        for (int h = 0; h < 2; h++) {
            #pragma unroll
            for (int m = 0; m < 4; m++)
                af[h][m] = *(const bf16x8*)(Cur + h * 8192 + (wave_m * 4 + m) * 1024 + lane_off);
            #pragma unroll
            for (int n = 0; n < 2; n++) {
                bv[h][n] = *(const bf16x8*)(Cur + 16384 + h * 4096 + (wave_n * 2 + n) * 1024 + lane_off);
                bg[h][n] = *(const bf16x8*)(Cur + 24576 + h * 4096 + (wave_n * 2 + n) * 1024 + lane_off);
            }
        }
        WAIT_LGKM0();
        BARRIER();           // all waves done reading this buffer -> safe to restage it

        if (kt < 14) G1_STAGE(Cur, (kt + 2) * 128);
        __builtin_amdgcn_sched_barrier(0);

        __builtin_amdgcn_s_setprio(1);
        #pragma unroll
        for (int h = 0; h < 2; h++)
            #pragma unroll
            for (int m = 0; m < 4; m++)
                #pragma unroll
                for (int n = 0; n < 2; n++) {
                    accV[m][n] = __builtin_amdgcn_mfma_f32_16x16x32_bf16(af[h][m], bv[h][n], accV[m][n], 0, 0, 0);
                    accG[m][n] = __builtin_amdgcn_mfma_f32_16x16x32_bf16(af[h][m], bg[h][n], accG[m][n], 0, 0, 0);
                }
        __builtin_amdgcn_s_setprio(0);
    }
#undef G1_STAGE

    // epilogue: silu-gate * router weight, bf16 store (slot order)
    int colF = nt * 64 + wave_n * 32 + (l & 15);
    int rowB = mt * 128 + wave_m * 64 + ((l >> 4) * 4);
    #pragma unroll
    for (int m = 0; m < 4; m++) {
        #pragma unroll
        for (int r = 0; r < 4; r++) {
            int srow = rowB + m * 16 + r;
            if (srow < cnt_e) {
                float wsc = wgs[off_e + srow];
                #pragma unroll
                for (int n = 0; n < 2; n++) {
                    float g = accG[m][n][r];
                    float v = accV[m][n][r];
                    float aa = wsc * v * g / (1.f + __expf(-g));
                    act[(size_t)(off_e + srow) * FDIM + colF + n * 16] = f2bf(aa);
                }
            }
        }
    }
}

// ============== GEMM2: dense grouped, 128x128, BK=64, depth-2 dbuf, counted vmcnt ==============
// 4 waves 2x2; wave = 64 rows x 64 C-cols. 64 KB LDS (2 x 32KB buffers).
__global__ __launch_bounds__(256, 2) void gemm2_kernel(
    const unsigned short* __restrict__ act,   // [NPAIR][FDIM] bf16, slot order (weighted)
    const unsigned short* __restrict__ W2b,   // [E][CDIM][FDIM] bf16
    const int* __restrict__ list, const int* __restrict__ cnt,
    const int* __restrict__ offs,
    unsigned short* __restrict__ eob)         // [NPAIR][CDIM] bf16, pair order
{
    int e = blockIdx.z, nt = blockIdx.x, mt = blockIdx.y;
    int cnt_e = cnt[e];
    if (mt * 128 >= cnt_e) return;
    int off_e = offs[e];
    const int* le = list + e * CAP;

    // per buffer (32KB): A k0 [0,8K) | A k1 [8K,16K) | B k0 [16K,24K) | B k1 [24K,32K)
    __shared__ __align__(16) char lds[65536];

    int t = threadIdx.x, l = t & 63, w = t >> 6;
    int wave_m = w >> 1, wave_n = w & 1;

    int c2s = ((t & 3) * 16) ^ (((t >> 5) & 1) << 5);
    int dst = t * 16;

    const char *sA0, *sA1, *sB0, *sB1;
    {
        int r0 = min(mt * 128 + (t >> 2), cnt_e - 1);
        int r1 = min(mt * 128 + 64 + (t >> 2), cnt_e - 1);
        sA0 = (const char*)act + (size_t)(off_e + r0) * 4096 + c2s;
        sA1 = (const char*)act + (size_t)(off_e + r1) * 4096 + c2s;
        int c0 = nt * 128 + (t >> 2);
        sB0 = (const char*)W2b + ((size_t)e * CDIM + c0) * 4096 + c2s;
        sB1 = sB0 + (size_t)64 * 4096;
    }

    int lane_off = (l & 15) * 64 + (((l >> 4) * 16) ^ (((l >> 3) & 1) << 5));
    f32x4 acc[4][4] = {};

#define G2_STAGE(BUF, KB) do { \
        gload_lds16(sA0 + (KB),      (BUF) + dst); \
        gload_lds16(sA1 + (KB),      (BUF) + 4096 + dst); \
        gload_lds16(sA0 + (KB) + 64, (BUF) + 8192 + dst); \
        gload_lds16(sA1 + (KB) + 64, (BUF) + 12288 + dst); \
        gload_lds16(sB0 + (KB),      (BUF) + 16384 + dst); \
        gload_lds16(sB1 + (KB),      (BUF) + 20480 + dst); \
        gload_lds16(sB0 + (KB) + 64, (BUF) + 24576 + dst); \
        gload_lds16(sB1 + (KB) + 64, (BUF) + 28672 + dst); \
    } while (0)

    G2_STAGE((char*)lds, 0);
    G2_STAGE((char*)lds + 32768, 128);

    for (int kt = 0; kt < 32; kt++) {
        if (kt == 31) { WAITVM(0); } else { WAITVM(8); }
        BARRIER();

        char* Cur = (char*)lds + (kt & 1) * 32768;
        bf16x8 af[2][4], bf[2][4];
        #pragma unroll
        for (int h = 0; h < 2; h++) {
            #pragma unroll
            for (int m = 0; m < 4; m++)
                af[h][m] = *(const bf16x8*)(Cur + h * 8192 + (wave_m * 4 + m) * 1024 + lane_off);
            #pragma unroll
            for (int n = 0; n < 4; n++)
                bf[h][n] = *(const bf16x8*)(Cur + 16384 + h * 8192 + (wave_n * 4 + n) * 1024 + lane_off);
        }
        WAIT_LGKM0();
        BARRIER();

        if (kt < 30) G2_STAGE(Cur, (kt + 2) * 128);
        __builtin_amdgcn_sched_barrier(0);

        __builtin_amdgcn_s_setprio(1);
        #pragma unroll
        for (int h = 0; h < 2; h++)
            #pragma unroll
            for (int m = 0; m < 4; m++)
                #pragma unroll
                for (int n = 0; n < 4; n++)
                    acc[m][n] = __builtin_amdgcn_mfma_f32_16x16x32_bf16(af[h][m], bf[h][n], acc[m][n], 0, 0, 0);
        __builtin_amdgcn_s_setprio(0);
    }
#undef G2_STAGE

    int colC = nt * 128 + wave_n * 64 + (l & 15);
    int rowB = mt * 128 + wave_m * 64 + ((l >> 4) * 4);
    #pragma unroll
    for (int m = 0; m < 4; m++) {
        #pragma unroll
        for (int r = 0; r < 4; r++) {
            int srow = rowB + m * 16 + r;
            if (srow < cnt_e) {
                int p = le[srow];
                #pragma unroll
                for (int n = 0; n < 4; n++)
                    eob[(size_t)p * CDIM + colC + n * 16] = f2bf(acc[m][n][r]);
            }
        }
    }
}

// ---------------- combine: out[t] = eo[2t] + eo[2t+1] (weights pre-folded) ----------------
__global__ __launch_bounds__(256) void combine_kernel(
    const unsigned short* __restrict__ eob, float* __restrict__ out)
{
    const long NG = (long)NTOK * (CDIM / 4);
    long i = (long)blockIdx.x * blockDim.x + threadIdx.x;
    long stride = (long)gridDim.x * blockDim.x;
    float4* out4 = (float4*)out;
    for (long g = i; g < NG; g += stride) {
        long t = g >> 8;
        long j = g & 255;
        uint2 a = ((const uint2*)(eob + (size_t)(2 * t) * CDIM))[j];
        uint2 b = ((const uint2*)(eob + (size_t)(2 * t + 1) * CDIM))[j];
        float4 o;
        o.x = bflo(a.x) + bflo(b.x);
        o.y = bfhi(a.x) + bfhi(b.x);
        o.z = bflo(a.y) + bflo(b.y);
        o.w = bfhi(a.y) + bfhi(b.y);
        out4[g] = o;
    }
}

// ---------------- launch ----------------
extern "C" void kernel_launch(void* const* d_in, const int* in_sizes, int n_in,
                              void* d_out, int out_size, void* d_ws, size_t ws_size,
                              hipStream_t stream) {
    const float* x  = (const float*)d_in[0];
    const float* Wr = (const float*)d_in[1];
    const float* W1 = (const float*)d_in[2];
    const float* W2 = (const float*)d_in[3];
    float* out = (float*)d_out;
    char* ws = (char*)d_ws;

    const size_t OFF_XG   = 0;
    const size_t OFF_W1B  = OFF_XG  + (size_t)NPAIR * CDIM * 2;           // 33,554,432
    const size_t OFF_ACT  = OFF_W1B + (size_t)NEXP * 2 * FDIM * CDIM * 2; // +67,108,864
    const size_t OFF_LIST = OFF_ACT + (size_t)NPAIR * FDIM * 2;           // +67,108,864
    const size_t OFF_WGT  = OFF_LIST + (size_t)NEXP * CAP * 4;
    const size_t OFF_WGS  = OFF_WGT + (size_t)NPAIR * 4;
    const size_t OFF_CNT  = OFF_WGS + (size_t)NPAIR * 4;
    const size_t OFF_OFFS = OFF_CNT + 32;
    const size_t OFF_EIDS = OFF_OFFS + 32;

    unsigned short* xg  = (unsigned short*)(ws + OFF_XG);
    unsigned short* W1b = (unsigned short*)(ws + OFF_W1B);
    unsigned short* act = (unsigned short*)(ws + OFF_ACT);
    int*   list = (int*)(ws + OFF_LIST);
    float* wgt  = (float*)(ws + OFF_WGT);
    float* wgs  = (float*)(ws + OFF_WGS);
    int*   cnt  = (int*)(ws + OFF_CNT);
    int*   offs = (int*)(ws + OFF_OFFS);
    int*   eids = (int*)(ws + OFF_EIDS);
    // overlays (dead-after-gemm1 regions):
    unsigned short* W2b = (unsigned short*)(ws + OFF_W1B);  // 33.5 MB <= 67 MB region
    unsigned short* eob = (unsigned short*)(ws + OFF_XG);   // 33.5 MB exactly

    hipMemsetAsync(cnt, 0, NEXP * sizeof(int), stream);

    cvt_kernel<<<4096, 256, 0, stream>>>(W1, W1b, (long)NEXP * 2 * FDIM * CDIM / 8);
    logits_kernel<<<NTOK / 4, 256, 0, stream>>>(x, Wr, wgt, eids);
    bucket_kernel<<<NTOK / 256, 256, 0, stream>>>(eids, list, cnt);
    offs_kernel<<<1, 64, 0, stream>>>(cnt, offs);
    pack_kernel<<<dim3(256, NEXP), 256, 0, stream>>>(x, list, cnt, offs, wgt, xg, wgs);

    gemm1_kernel<<<dim3(FDIM / 64, MTCAP, NEXP), 256, 0, stream>>>(xg, W1b, wgs, act, cnt, offs);

    cvt_kernel<<<4096, 256, 0, stream>>>(W2, W2b, (long)NEXP * CDIM * FDIM / 8);

    gemm2_kernel<<<dim3(CDIM / 128, MTCAP, NEXP), 256, 0, stream>>>(act, W2b, list, cnt, offs, eob);
    combine_kernel<<<2048, 256, 0, stream>>>(eob, out);
}

// Round 10
// 357.894 us; speedup vs baseline: 1.0281x; 1.0281x over previous
//
#include <hip/hip_runtime.h>

// ---------------- problem constants ----------------
#define NTOK 8192      // B*T
#define CDIM 1024      // C
#define FDIM 2048      // F
#define NEXP 8         // E
#define CAP  16384     // per-expert list stride
#define NPAIR 16384    // N*K
#define MTCAP 32       // 32*128 = 4096 rows/expert capacity

typedef __bf16 bf16x8 __attribute__((ext_vector_type(8)));
typedef float  f32x4  __attribute__((ext_vector_type(4)));

__device__ __forceinline__ unsigned short f2bf(float f) {
    unsigned int u = __builtin_bit_cast(unsigned int, f);
    unsigned int r = (u + 0x7FFFu + ((u >> 16) & 1u)) >> 16;
    return (unsigned short)r;
}

__device__ __forceinline__ unsigned int pack2(float lo, float hi) {
    return ((unsigned int)f2bf(hi) << 16) | (unsigned int)f2bf(lo);
}

__device__ __forceinline__ float bflo(unsigned int u) {
    return __builtin_bit_cast(float, u << 16);
}
__device__ __forceinline__ float bfhi(unsigned int u) {
    return __builtin_bit_cast(float, u & 0xFFFF0000u);
}

__device__ __forceinline__ void gload_lds16(const void* g, void* l) {
    __builtin_amdgcn_global_load_lds(
        (const __attribute__((address_space(1))) unsigned int*)g,
        (__attribute__((address_space(3))) unsigned int*)l, 16, 0, 0);
}

#define BARRIER() asm volatile("s_barrier" ::: "memory")
#define WAIT_LGKM0() do { asm volatile("s_waitcnt lgkmcnt(0)" ::: "memory"); __builtin_amdgcn_sched_barrier(0); } while (0)
#define WAITVM0() asm volatile("s_waitcnt vmcnt(0)" ::: "memory")

// ---------------- fp32 -> bf16 bulk convert ----------------
__global__ void cvt_kernel(const float* __restrict__ s, unsigned short* __restrict__ d, long ngrp) {
    long i = (long)blockIdx.x * blockDim.x + threadIdx.x;
    long stride = (long)gridDim.x * blockDim.x;
    const float4* s4 = (const float4*)s;
    uint4* d4 = (uint4*)d;
    for (long g = i; g < ngrp; g += stride) {
        float4 a = s4[2 * g], b = s4[2 * g + 1];
        uint4 o;
        o.x = pack2(a.x, a.y); o.y = pack2(a.z, a.w);
        o.z = pack2(b.x, b.y); o.w = pack2(b.z, b.w);
        d4[g] = o;
    }
}

// ---------------- logits: top-2 + softmax weights, NO atomics ----------------
__global__ __launch_bounds__(256) void logits_kernel(
    const float* __restrict__ x, const float* __restrict__ Wr,
    float* __restrict__ wgt, int* __restrict__ eids)
{
    int w = threadIdx.x >> 6, l = threadIdx.x & 63;
    int t = blockIdx.x * 4 + w;
    const float* xr = x + (size_t)t * CDIM;
    float acc[NEXP];
    #pragma unroll
    for (int e = 0; e < NEXP; e++) acc[e] = 0.f;
    for (int c = l; c < CDIM; c += 64) {
        float xv = xr[c];
        #pragma unroll
        for (int e = 0; e < NEXP; e++) acc[e] += xv * Wr[e * CDIM + c];
    }
    #pragma unroll
    for (int e = 0; e < NEXP; e++)
        for (int off = 32; off > 0; off >>= 1) acc[e] += __shfl_down(acc[e], off);
    if (l == 0) {
        int i0 = 0; float l0 = acc[0];
        #pragma unroll
        for (int e = 1; e < NEXP; e++) if (acc[e] > l0) { l0 = acc[e]; i0 = e; }
        int i1 = -1; float l1 = -3.4e38f;
        #pragma unroll
        for (int e = 0; e < NEXP; e++) if (e != i0 && acc[e] > l1) { l1 = acc[e]; i1 = e; }
        float tv = __expf(l1 - l0);
        float den = 1.f + tv;
        wgt[2 * t] = 1.f / den;
        wgt[2 * t + 1] = tv / den;
        eids[t] = i0 | (i1 << 8);
    }
}

// ---------------- bucket: per-block LDS counters -> 8 global atomics/block ----------------
__global__ __launch_bounds__(256) void bucket_kernel(
    const int* __restrict__ eids, int* __restrict__ list, int* __restrict__ cnt)
{
    __shared__ int lcnt[NEXP];
    __shared__ int lbase[NEXP];
    int t = threadIdx.x;
    if (t < NEXP) lcnt[t] = 0;
    __syncthreads();
    int tok = blockIdx.x * 256 + t;
    int id = eids[tok];
    int e0 = id & 0xff, e1 = (id >> 8) & 0xff;
    int s0 = atomicAdd(&lcnt[e0], 1);
    int s1 = atomicAdd(&lcnt[e1], 1);
    __syncthreads();
    if (t < NEXP) lbase[t] = atomicAdd(&cnt[t], lcnt[t]);
    __syncthreads();
    list[e0 * CAP + lbase[e0] + s0] = 2 * tok;
    list[e1 * CAP + lbase[e1] + s1] = 2 * tok + 1;
}

// ---------------- offs: serial 8-entry prefix sum ----------------
__global__ void offs_kernel(const int* __restrict__ cnt, int* __restrict__ offs) {
    if (threadIdx.x == 0) {
        int a = 0;
        for (int e = 0; e < NEXP; e++) { offs[e] = a; a += cnt[e]; }
    }
}

// ---------------- pack: xg[offs[e]+s] = bf16(x[tok]); wgs[offs[e]+s] = wgt[p] ----------------
__global__ __launch_bounds__(256) void pack_kernel(
    const float* __restrict__ x, const int* __restrict__ list,
    const int* __restrict__ cnt, const int* __restrict__ offs,
    const float* __restrict__ wgt,
    unsigned short* __restrict__ xg, float* __restrict__ wgs)
{
    int e = blockIdx.y;
    int cnt_e = cnt[e];
    int s0 = blockIdx.x * 16;
    if (s0 >= cnt_e) return;
    int t = threadIdx.x;
    int sr = s0 + (t >> 4);
    if (sr >= cnt_e) return;
    int p = list[e * CAP + sr];
    int tok = p >> 1;
    if ((t & 15) == 0) wgs[offs[e] + sr] = wgt[p];
    const float4* src = (const float4*)(x + (size_t)tok * CDIM);
    uint2* dst = (uint2*)(xg + (size_t)(offs[e] + sr) * CDIM);
    int c = t & 15;
    #pragma unroll
    for (int i = 0; i < 16; i++) {
        float4 v = src[c + i * 16];
        uint2 o; o.x = pack2(v.x, v.y); o.y = pack2(v.z, v.w);
        dst[c + i * 16] = o;
    }
}

// ============== GEMM1: dense grouped, 128x64(V+G), BK=64, stage-early drain-late ==============
// Round-8 proven structure + FULL UNROLL: staging offsets become instruction immediates
// (compiler folds sA+const into offset: field), killing per-iter VALU address math.
__global__ __launch_bounds__(256, 2) void gemm1_kernel(
    const unsigned short* __restrict__ xg,    // [NPAIR][CDIM] bf16, slot order
    const unsigned short* __restrict__ W1b,   // [E][2F][CDIM] bf16
    const float* __restrict__ wgs,            // [NPAIR] slot-order router weight
    unsigned short* __restrict__ act,         // [NPAIR][FDIM] bf16, slot order (weighted)
    const int* __restrict__ cnt, const int* __restrict__ offs)
{
    int e = blockIdx.z, nt = blockIdx.x, mt = blockIdx.y;
    int cnt_e = cnt[e];
    if (mt * 128 >= cnt_e) return;
    int off_e = offs[e];

    // LDS 32KB: A k0 [0,8K) | A k1 [8K,16K) | Bv k0/k1 [16K,24K) | Bg k0/k1 [24K,32K)
    __shared__ __align__(16) char lds[32768];

    int t = threadIdx.x, l = t & 63, w = t >> 6;
    int wave_m = w >> 1, wave_n = w & 1;

    int c2s = ((t & 3) * 16) ^ (((t >> 5) & 1) << 5);
    int dst = t * 16;

    const char *sA0, *sA1, *sBv, *sBg;
    {
        int r0 = min(mt * 128 + (t >> 2), cnt_e - 1);
        int r1 = min(mt * 128 + 64 + (t >> 2), cnt_e - 1);
        sA0 = (const char*)xg + (size_t)(off_e + r0) * 2048 + c2s;
        sA1 = (const char*)xg + (size_t)(off_e + r1) * 2048 + c2s;
        int f = nt * 64 + (t >> 2);
        sBv = (const char*)W1b + ((size_t)e * 2 * FDIM + f) * 2048 + c2s;
        sBg = sBv + (size_t)FDIM * 2048;
    }

    int lane_off = (l & 15) * 64 + (((l >> 4) * 16) ^ (((l >> 3) & 1) << 5));
    f32x4 accV[4][2] = {}, accG[4][2] = {};

#define G1_STAGE(KB) do { \
        gload_lds16(sA0 + (KB),      (char*)lds + dst); \
        gload_lds16(sA1 + (KB),      (char*)lds + 4096 + dst); \
        gload_lds16(sA0 + (KB) + 64, (char*)lds + 8192 + dst); \
        gload_lds16(sA1 + (KB) + 64, (char*)lds + 12288 + dst); \
        gload_lds16(sBv + (KB),      (char*)lds + 16384 + dst); \
        gload_lds16(sBv + (KB) + 64, (char*)lds + 20480 + dst); \
        gload_lds16(sBg + (KB),      (char*)lds + 24576 + dst); \
        gload_lds16(sBg + (KB) + 64, (char*)lds + 28672 + dst); \
    } while (0)

    G1_STAGE(0);   // prologue: tile 0

    #pragma unroll
    for (int kt = 0; kt < 16; kt++) {
        WAITVM0();
        BARRIER();

        bf16x8 af[2][4], bv[2][2], bg[2][2];
        #pragma unroll
        for (int h = 0; h < 2; h++) {
            #pragma unroll
            for (int m = 0; m < 4; m++)
                af[h][m] = *(const bf16x8*)((char*)lds + h * 8192 + (wave_m * 4 + m) * 1024 + lane_off);
            #pragma unroll
            for (int n = 0; n < 2; n++) {
                bv[h][n] = *(const bf16x8*)((char*)lds + 16384 + h * 4096 + (wave_n * 2 + n) * 1024 + lane_off);
                bg[h][n] = *(const bf16x8*)((char*)lds + 24576 + h * 4096 + (wave_n * 2 + n) * 1024 + lane_off);
            }
        }
        WAIT_LGKM0();
        BARRIER();           // all waves done reading LDS -> safe to overwrite

        if (kt != 15) { int kb = (kt + 1) * 128; G1_STAGE(kb); }
        __builtin_amdgcn_sched_barrier(0);

        __builtin_amdgcn_s_setprio(1);
        #pragma unroll
        for (int h = 0; h < 2; h++)
            #pragma unroll
            for (int m = 0; m < 4; m++)
                #pragma unroll
                for (int n = 0; n < 2; n++) {
                    accV[m][n] = __builtin_amdgcn_mfma_f32_16x16x32_bf16(af[h][m], bv[h][n], accV[m][n], 0, 0, 0);
                    accG[m][n] = __builtin_amdgcn_mfma_f32_16x16x32_bf16(af[h][m], bg[h][n], accG[m][n], 0, 0, 0);
                }
        __builtin_amdgcn_s_setprio(0);
    }
#undef G1_STAGE

    // epilogue: silu-gate * router weight, bf16 store (slot order)
    int colF = nt * 64 + wave_n * 32 + (l & 15);
    int rowB = mt * 128 + wave_m * 64 + ((l >> 4) * 4);
    #pragma unroll
    for (int m = 0; m < 4; m++) {
        #pragma unroll
        for (int r = 0; r < 4; r++) {
            int srow = rowB + m * 16 + r;
            if (srow < cnt_e) {
                float wsc = wgs[off_e + srow];
                #pragma unroll
                for (int n = 0; n < 2; n++) {
                    float g = accG[m][n][r];
                    float v = accV[m][n][r];
                    float aa = wsc * v * g / (1.f + __expf(-g));
                    act[(size_t)(off_e + srow) * FDIM + colF + n * 16] = f2bf(aa);
                }
            }
        }
    }
}

// ============== GEMM2: dense grouped, 128x128, BK=64, stage-early drain-late, full unroll ==============
__global__ __launch_bounds__(256, 2) void gemm2_kernel(
    const unsigned short* __restrict__ act,   // [NPAIR][FDIM] bf16, slot order (weighted)
    const unsigned short* __restrict__ W2b,   // [E][CDIM][FDIM] bf16
    const int* __restrict__ list, const int* __restrict__ cnt,
    const int* __restrict__ offs,
    unsigned short* __restrict__ eob)         // [NPAIR][CDIM] bf16, pair order
{
    int e = blockIdx.z, nt = blockIdx.x, mt = blockIdx.y;
    int cnt_e = cnt[e];
    if (mt * 128 >= cnt_e) return;
    int off_e = offs[e];
    const int* le = list + e * CAP;

    // LDS 32KB: A k0 [0,8K) | A k1 [8K,16K) | B k0 [16K,24K) | B k1 [24K,32K)
    __shared__ __align__(16) char lds[32768];

    int t = threadIdx.x, l = t & 63, w = t >> 6;
    int wave_m = w >> 1, wave_n = w & 1;

    int c2s = ((t & 3) * 16) ^ (((t >> 5) & 1) << 5);
    int dst = t * 16;

    const char *sA0, *sA1, *sB0, *sB1;
    {
        int r0 = min(mt * 128 + (t >> 2), cnt_e - 1);
        int r1 = min(mt * 128 + 64 + (t >> 2), cnt_e - 1);
        sA0 = (const char*)act + (size_t)(off_e + r0) * 4096 + c2s;
        sA1 = (const char*)act + (size_t)(off_e + r1) * 4096 + c2s;
        int c0 = nt * 128 + (t >> 2);
        sB0 = (const char*)W2b + ((size_t)e * CDIM + c0) * 4096 + c2s;
        sB1 = sB0 + (size_t)64 * 4096;
    }

    int lane_off = (l & 15) * 64 + (((l >> 4) * 16) ^ (((l >> 3) & 1) << 5));
    f32x4 acc[4][4] = {};

#define G2_STAGE(KB) do { \
        gload_lds16(sA0 + (KB),      (char*)lds + dst); \
        gload_lds16(sA1 + (KB),      (char*)lds + 4096 + dst); \
        gload_lds16(sA0 + (KB) + 64, (char*)lds + 8192 + dst); \
        gload_lds16(sA1 + (KB) + 64, (char*)lds + 12288 + dst); \
        gload_lds16(sB0 + (KB),      (char*)lds + 16384 + dst); \
        gload_lds16(sB1 + (KB),      (char*)lds + 20480 + dst); \
        gload_lds16(sB0 + (KB) + 64, (char*)lds + 24576 + dst); \
        gload_lds16(sB1 + (KB) + 64, (char*)lds + 28672 + dst); \
    } while (0)

    G2_STAGE(0);

    #pragma unroll
    for (int kt = 0; kt < 32; kt++) {
        WAITVM0();
        BARRIER();

        bf16x8 af[2][4], bf[2][4];
        #pragma unroll
        for (int h = 0; h < 2; h++) {
            #pragma unroll
            for (int m = 0; m < 4; m++)
                af[h][m] = *(const bf16x8*)((char*)lds + h * 8192 + (wave_m * 4 + m) * 1024 + lane_off);
            #pragma unroll
            for (int n = 0; n < 4; n++)
                bf[h][n] = *(const bf16x8*)((char*)lds + 16384 + h * 8192 + (wave_n * 4 + n) * 1024 + lane_off);
        }
        WAIT_LGKM0();
        BARRIER();

        if (kt != 31) { int kb = (kt + 1) * 128; G2_STAGE(kb); }
        __builtin_amdgcn_sched_barrier(0);

        __builtin_amdgcn_s_setprio(1);
        #pragma unroll
        for (int h = 0; h < 2; h++)
            #pragma unroll
            for (int m = 0; m < 4; m++)
                #pragma unroll
                for (int n = 0; n < 4; n++)
                    acc[m][n] = __builtin_amdgcn_mfma_f32_16x16x32_bf16(af[h][m], bf[h][n], acc[m][n], 0, 0, 0);
        __builtin_amdgcn_s_setprio(0);
    }
#undef G2_STAGE

    int colC = nt * 128 + wave_n * 64 + (l & 15);
    int rowB = mt * 128 + wave_m * 64 + ((l >> 4) * 4);
    #pragma unroll
    for (int m = 0; m < 4; m++) {
        #pragma unroll
        for (int r = 0; r < 4; r++) {
            int srow = rowB + m * 16 + r;
            if (srow < cnt_e) {
                int p = le[srow];
                #pragma unroll
                for (int n = 0; n < 4; n++)
                    eob[(size_t)p * CDIM + colC + n * 16] = f2bf(acc[m][n][r]);
            }
        }
    }
}

// ---------------- combine: out[t] = eo[2t] + eo[2t+1] (weights pre-folded) ----------------
__global__ __launch_bounds__(256) void combine_kernel(
    const unsigned short* __restrict__ eob, float* __restrict__ out)
{
    const long NG = (long)NTOK * (CDIM / 4);
    long i = (long)blockIdx.x * blockDim.x + threadIdx.x;
    long stride = (long)gridDim.x * blockDim.x;
    float4* out4 = (float4*)out;
    for (long g = i; g < NG; g += stride) {
        long t = g >> 8;
        long j = g & 255;
        uint2 a = ((const uint2*)(eob + (size_t)(2 * t) * CDIM))[j];
        uint2 b = ((const uint2*)(eob + (size_t)(2 * t + 1) * CDIM))[j];
        float4 o;
        o.x = bflo(a.x) + bflo(b.x);
        o.y = bfhi(a.x) + bfhi(b.x);
        o.z = bflo(a.y) + bflo(b.y);
        o.w = bfhi(a.y) + bfhi(b.y);
        out4[g] = o;
    }
}

// ---------------- launch ----------------
extern "C" void kernel_launch(void* const* d_in, const int* in_sizes, int n_in,
                              void* d_out, int out_size, void* d_ws, size_t ws_size,
                              hipStream_t stream) {
    const float* x  = (const float*)d_in[0];
    const float* Wr = (const float*)d_in[1];
    const float* W1 = (const float*)d_in[2];
    const float* W2 = (const float*)d_in[3];
    float* out = (float*)d_out;
    char* ws = (char*)d_ws;

    const size_t OFF_XG   = 0;
    const size_t OFF_W1B  = OFF_XG  + (size_t)NPAIR * CDIM * 2;           // 33,554,432
    const size_t OFF_ACT  = OFF_W1B + (size_t)NEXP * 2 * FDIM * CDIM * 2; // +67,108,864
    const size_t OFF_LIST = OFF_ACT + (size_t)NPAIR * FDIM * 2;           // +67,108,864
    const size_t OFF_WGT  = OFF_LIST + (size_t)NEXP * CAP * 4;
    const size_t OFF_WGS  = OFF_WGT + (size_t)NPAIR * 4;
    const size_t OFF_CNT  = OFF_WGS + (size_t)NPAIR * 4;
    const size_t OFF_OFFS = OFF_CNT + 32;
    const size_t OFF_EIDS = OFF_OFFS + 32;

    unsigned short* xg  = (unsigned short*)(ws + OFF_XG);
    unsigned short* W1b = (unsigned short*)(ws + OFF_W1B);
    unsigned short* act = (unsigned short*)(ws + OFF_ACT);
    int*   list = (int*)(ws + OFF_LIST);
    float* wgt  = (float*)(ws + OFF_WGT);
    float* wgs  = (float*)(ws + OFF_WGS);
    int*   cnt  = (int*)(ws + OFF_CNT);
    int*   offs = (int*)(ws + OFF_OFFS);
    int*   eids = (int*)(ws + OFF_EIDS);
    // overlays (dead-after-gemm1 regions):
    unsigned short* W2b = (unsigned short*)(ws + OFF_W1B);  // 33.5 MB <= 67 MB region
    unsigned short* eob = (unsigned short*)(ws + OFF_XG);   // 33.5 MB exactly

    hipMemsetAsync(cnt, 0, NEXP * sizeof(int), stream);

    cvt_kernel<<<4096, 256, 0, stream>>>(W1, W1b, (long)NEXP * 2 * FDIM * CDIM / 8);
    logits_kernel<<<NTOK / 4, 256, 0, stream>>>(x, Wr, wgt, eids);
    bucket_kernel<<<NTOK / 256, 256, 0, stream>>>(eids, list, cnt);
    offs_kernel<<<1, 64, 0, stream>>>(cnt, offs);
    pack_kernel<<<dim3(256, NEXP), 256, 0, stream>>>(x, list, cnt, offs, wgt, xg, wgs);

    gemm1_kernel<<<dim3(FDIM / 64, MTCAP, NEXP), 256, 0, stream>>>(xg, W1b, wgs, act, cnt, offs);

    cvt_kernel<<<4096, 256, 0, stream>>>(W2, W2b, (long)NEXP * CDIM * FDIM / 8);

    gemm2_kernel<<<dim3(CDIM / 128, MTCAP, NEXP), 256, 0, stream>>>(act, W2b, list, cnt, offs, eob);
    combine_kernel<<<2048, 256, 0, stream>>>(eob, out);
}